// Round 7
// baseline (691.436 us; speedup 1.0000x reference)
//
#include <hip/hip_runtime.h>
#include <math.h>

#define B_ 4
#define S_ 2048
#define D_ 2048
#define H_ 16
#define DH_ 128

typedef unsigned short u16;
typedef unsigned int u32;
typedef u16 u16x8 __attribute__((ext_vector_type(8)));
typedef __bf16 bf16x8 __attribute__((ext_vector_type(8)));
typedef float f32x4 __attribute__((ext_vector_type(4)));
typedef float f32x16 __attribute__((ext_vector_type(16)));

__device__ inline u16 f2bf(float f) {
    // round-to-nearest-even fp32 -> bf16 (inputs are finite)
    unsigned int u = __builtin_bit_cast(unsigned int, f);
    unsigned int lsb = (u >> 16) & 1u;
    u += 0x7fffu + lsb;
    return (u16)(u >> 16);
}

__device__ inline f32x4 mfma16(u16x8 a, u16x8 b, f32x4 c) {
    return __builtin_amdgcn_mfma_f32_16x16x32_bf16(
        __builtin_bit_cast(bf16x8, a), __builtin_bit_cast(bf16x8, b), c, 0, 0, 0);
}

__device__ inline f32x16 mfma32(u16x8 a, u16x8 b, f32x16 c) {
    return __builtin_amdgcn_mfma_f32_32x32x16_bf16(
        __builtin_bit_cast(bf16x8, a), __builtin_bit_cast(bf16x8, b), c, 0, 0, 0);
}

// async global->LDS, 16B per lane; LDS dest = wave-uniform base + lane*16
__device__ inline void gl2lds16(const u16* g, u16* l) {
    __builtin_amdgcn_global_load_lds(
        (const __attribute__((address_space(1))) void*)g,
        (__attribute__((address_space(3))) void*)l, 16, 0, 0);
}

// raw barrier (no vmcnt drain) with compiler memory fences on both sides
__device__ inline void block_barrier() {
    asm volatile("" ::: "memory");
    __builtin_amdgcn_s_barrier();
    asm volatile("" ::: "memory");
}

// ---------------- fp32 -> bf16 conversion (8 elems/thread) ----------------
__global__ __launch_bounds__(256) void cvt_f32_bf16(const float* __restrict__ src,
                                                    u16* __restrict__ dst, int n8) {
    int i = blockIdx.x * 256 + threadIdx.x;
    if (i >= n8) return;
    const float4* s = (const float4*)src + (size_t)i * 2;
    float4 a = s[0], b = s[1];
    u16x8 o;
    o[0] = f2bf(a.x); o[1] = f2bf(a.y); o[2] = f2bf(a.z); o[3] = f2bf(a.w);
    o[4] = f2bf(b.x); o[5] = f2bf(b.y); o[6] = f2bf(b.z); o[7] = f2bf(b.w);
    *((u16x8*)dst + i) = o;
}

// 4 weight matrices (sources separate, dests contiguous) in one dispatch
__global__ __launch_bounds__(256) void cvt4_f32_bf16(const float* __restrict__ s0,
                                                     const float* __restrict__ s1,
                                                     const float* __restrict__ s2,
                                                     const float* __restrict__ s3,
                                                     u16* __restrict__ dst) {
    const int region = blockIdx.x >> 11;         // 2048 blocks per 4M-elem matrix
    const int i = (blockIdx.x & 2047) * 256 + threadIdx.x;  // < 524288 always
    const float* src = region == 0 ? s0 : region == 1 ? s1 : region == 2 ? s2 : s3;
    const float4* s = (const float4*)src + (size_t)i * 2;
    float4 a = s[0], b = s[1];
    u16x8 o;
    o[0] = f2bf(a.x); o[1] = f2bf(a.y); o[2] = f2bf(a.z); o[3] = f2bf(a.w);
    o[4] = f2bf(b.x); o[5] = f2bf(b.y); o[6] = f2bf(b.z); o[7] = f2bf(b.w);
    *((u16x8*)dst + (size_t)region * 524288 + i) = o;
}

// ---------------- C[M,N] = A[M,K] * B[N,K]^T ------------------------------
// 256x256 tile, BK=64, 8 waves (2M x 4N), 4-phase/K-tile schedule, counted
// vmcnt(6). Round 7: fragment shape 16x16x32 -> 32x32x16. Round-6 counters
// (MfmaUtil 31.7%, conflicts 0, VALU 16%, no spill, HBM 30%) isolate the
// bottleneck as MFMA ISSUE RATE at 2 waves/SIMD: a 16x16x32 per-wave cadence
// (~16cy) can't fill the pipe with 2 issuers; 32x32x16 does 2x work/inst so
// 2 waves suffice (HK/AITER use 32x32 throughout; m119: 32x32 ceiling 2495TF).
// Per wave: 4x2 tiles of 32x32, acc = 8 x f32x16 (128 VGPR, unchanged).
// LDS swizzle unchanged (LDS[row][c ^ (row&7)], 16B chunks); 32-row b128 reads
// stay conflict-free (8 lanes/chunk x 4 dwords = 8 dwords/bank = b128 minimum).
// C/D map [guide m74/m101]: col=lane&31, row=(reg&3)+8*(reg>>2)+4*(lane>>5).
template <typename OutT>
__device__ __forceinline__ void gemm_core(const u16* __restrict__ A,
                                          const u16* __restrict__ Bw,
                                          const float* __restrict__ bias,
                                          const float* __restrict__ helix,
                                          OutT* __restrict__ C,
                                          int N, int K,
                                          int tm, int tn, int gate, int vout) {
    __shared__ __align__(16) u16 As[2][256 * 64];
    __shared__ __align__(16) u16 Bs[2][256 * 64];

    const int tid = threadIdx.x;
    const int lane = tid & 63, w = tid >> 6;
    const int r32 = lane & 31, hi = lane >> 5;
    const int wm = w & 1, wn = w >> 1;
    const int NT = K >> 6;  // K-tiles of 64

    const u16* Asrc = A + (size_t)(tm * 256) * K;
    const u16* Bsrc = Bw + (size_t)(tn * 256) * K;

    u32 go[4][2];
    u32 lo[4][2];
#pragma unroll
    for (int q = 0; q < 2; ++q) {
        const int seg = w * 2 + q;          // 0..15
        const int i0 = seg * 8 + (lane >> 3);
        const int s0 = seg * 8;
        // U0: A rows {0-63, 128-191} (read in phases 0-1)
        int row = (i0 & 63) | ((i0 >> 6) << 7);
        int rb = (s0 & 63) | ((s0 >> 6) << 7);
        go[0][q] = (u32)row * K + (((lane & 7) ^ (row & 7)) << 3);
        lo[0][q] = rb << 6;
        // U3: A rows {64-127, 192-255} (read in phases 2-3)
        row += 64; rb += 64;
        go[3][q] = (u32)row * K + (((lane & 7) ^ (row & 7)) << 3);
        lo[3][q] = rb << 6;
        // U1: B rows offset 0-31 (mod 64) (read phases 0-3)
        row = (i0 & 31) | ((i0 >> 5) << 6);
        rb = (s0 & 31) | ((s0 >> 5) << 6);
        go[1][q] = (u32)row * K + (((lane & 7) ^ (row & 7)) << 3);
        lo[1][q] = rb << 6;
        // U2: B rows offset 32-63 (read phases 0-3)
        row += 32; rb += 32;
        go[2][q] = (u32)row * K + (((lane & 7) ^ (row & 7)) << 3);
        lo[2][q] = rb << 6;
    }

#define STAGE(u, tt)                                                          \
    do {                                                                      \
        const int kt_ = (((tt) < NT) ? (tt) : (NT - 1)) << 6;                 \
        const u16* gb_ = ((u) == 1 || (u) == 2) ? Bsrc : Asrc;                \
        u16* lb_ = ((u) == 1 || (u) == 2) ? Bs[(tt) & 1] : As[(tt) & 1];      \
        gl2lds16(gb_ + go[u][0] + kt_, lb_ + lo[u][0]);                       \
        gl2lds16(gb_ + go[u][1] + kt_, lb_ + lo[u][1]);                       \
    } while (0)

    // fragment addressing: row = band + r32, k-chunk(kk) = kk*2 + hi, swizzled
    // by ^(row&7) = ^(r32&7). Units: u16.
    int kcs[4];
#pragma unroll
    for (int kk = 0; kk < 4; ++kk) kcs[kk] = (((kk * 2 + hi) ^ (r32 & 7)) * 8);
    const int rA0 = (wm * 128 + r32) * 64;  // + mt*2048
    const int rB0 = (wn * 64 + r32) * 64;   // + nt*2048

    f32x16 acc[4][2];
#pragma unroll
    for (int mt = 0; mt < 4; ++mt)
#pragma unroll
        for (int nt = 0; nt < 2; ++nt)
#pragma unroll
            for (int e = 0; e < 16; ++e) acc[mt][nt][e] = 0.f;

    u16x8 af[2][4], bf[2][4];

    STAGE(0, 0); STAGE(1, 0); STAGE(2, 0); STAGE(3, 0);
    STAGE(0, 1); STAGE(1, 1); STAGE(2, 1);
    asm volatile("s_waitcnt vmcnt(6)" ::: "memory");
    block_barrier();

    for (int t = 0; t < NT; ++t) {
        const u16* Ab = As[t & 1];
        const u16* Bb = Bs[t & 1];

        // ---- phase 0: read A mt0-1 (all kk) + B kk0-1; stage U3(t+1)
#pragma unroll
        for (int mt = 0; mt < 2; ++mt)
#pragma unroll
            for (int kk = 0; kk < 4; ++kk)
                af[mt][kk] = *(const u16x8*)&Ab[rA0 + mt * 2048 + kcs[kk]];
#pragma unroll
        for (int nt = 0; nt < 2; ++nt)
#pragma unroll
            for (int kk = 0; kk < 2; ++kk)
                bf[nt][kk] = *(const u16x8*)&Bb[rB0 + nt * 2048 + kcs[kk]];
        STAGE(3, t + 1);
        block_barrier();
        asm volatile("s_waitcnt lgkmcnt(0)" ::: "memory");
        __builtin_amdgcn_s_setprio(1);
#pragma unroll
        for (int kk = 0; kk < 2; ++kk)
#pragma unroll
            for (int mt = 0; mt < 2; ++mt)
#pragma unroll
                for (int nt = 0; nt < 2; ++nt)
                    acc[mt][nt] = mfma32(af[mt][kk], bf[nt][kk], acc[mt][nt]);
        __builtin_amdgcn_s_setprio(0);
        block_barrier();

        // ---- phase 1: read B kk2-3; stage U0(t+2)
#pragma unroll
        for (int nt = 0; nt < 2; ++nt)
#pragma unroll
            for (int kk = 2; kk < 4; ++kk)
                bf[nt][kk] = *(const u16x8*)&Bb[rB0 + nt * 2048 + kcs[kk]];
        STAGE(0, t + 2);
        block_barrier();
        asm volatile("s_waitcnt lgkmcnt(0)" ::: "memory");
        __builtin_amdgcn_s_setprio(1);
#pragma unroll
        for (int kk = 2; kk < 4; ++kk)
#pragma unroll
            for (int mt = 0; mt < 2; ++mt)
#pragma unroll
                for (int nt = 0; nt < 2; ++nt)
                    acc[mt][nt] = mfma32(af[mt][kk], bf[nt][kk], acc[mt][nt]);
        __builtin_amdgcn_s_setprio(0);
        block_barrier();

        // ---- phase 2: read A mt2-3 (all kk); stage U1(t+2)
#pragma unroll
        for (int mt = 0; mt < 2; ++mt)
#pragma unroll
            for (int kk = 0; kk < 4; ++kk)
                af[mt][kk] = *(const u16x8*)&Ab[rA0 + (2 + mt) * 2048 + kcs[kk]];
        STAGE(1, t + 2);
        block_barrier();
        asm volatile("s_waitcnt lgkmcnt(0)" ::: "memory");
        __builtin_amdgcn_s_setprio(1);
#pragma unroll
        for (int kk = 0; kk < 2; ++kk)
#pragma unroll
            for (int mt = 0; mt < 2; ++mt)
#pragma unroll
                for (int nt = 0; nt < 2; ++nt)
                    acc[2 + mt][nt] = mfma32(af[mt][kk], bf[nt][kk], acc[2 + mt][nt]);
        __builtin_amdgcn_s_setprio(0);
        block_barrier();

        // ---- phase 3: stage U2(t+2); counted vmcnt(6) -> tile t+1 confirmed
        STAGE(2, t + 2);
        asm volatile("s_waitcnt vmcnt(6)" ::: "memory");
        block_barrier();
        __builtin_amdgcn_s_setprio(1);
#pragma unroll
        for (int kk = 2; kk < 4; ++kk)
#pragma unroll
            for (int mt = 0; mt < 2; ++mt)
#pragma unroll
                for (int nt = 0; nt < 2; ++nt)
                    acc[2 + mt][nt] = mfma32(af[mt][kk], bf[nt][kk], acc[2 + mt][nt]);
        __builtin_amdgcn_s_setprio(0);
        block_barrier();
    }
    asm volatile("s_waitcnt vmcnt(0)" ::: "memory");  // drain clamped tail stages
#undef STAGE

    // epilogue: acc[mt][nt][reg] -> row = tm*256+wm*128+mt*32+(reg&3)+8*(reg>>2)+4*hi
    //                               col = tn*256+wn*64+nt*32+r32
    if (vout) {
        // V-mode: row = d in [0,D), col = global t in [0,B*S); bias on row
#pragma unroll
        for (int mt = 0; mt < 4; ++mt)
#pragma unroll
            for (int reg = 0; reg < 16; ++reg) {
                int row = tm * 256 + wm * 128 + mt * 32 + (reg & 3) + 8 * (reg >> 2) + 4 * hi;
                float bs = bias[row];
#pragma unroll
                for (int nt = 0; nt < 2; ++nt) {
                    int col = tn * 256 + wn * 64 + nt * 32 + r32;
                    float val = acc[mt][nt][reg] + bs;
                    ((u16*)C)[(size_t)(col >> 11) * ((size_t)D_ * S_) +
                              (size_t)row * S_ + (col & (S_ - 1))] = f2bf(val);
                }
            }
    } else {
#pragma unroll
        for (int nt = 0; nt < 2; ++nt) {
            int col = tn * 256 + wn * 64 + nt * 32 + r32;
            float bs = bias[col];
            float g = 1.0f;
            if (gate == 1) g = cosf(helix[col]);
            if (gate == 2) g = sinf(helix[col]);
#pragma unroll
            for (int mt = 0; mt < 4; ++mt)
#pragma unroll
                for (int reg = 0; reg < 16; ++reg) {
                    int row = tm * 256 + wm * 128 + mt * 32 + (reg & 3) + 8 * (reg >> 2) + 4 * hi;
                    float val = (acc[mt][nt][reg] + bs) * g;
                    if constexpr (sizeof(OutT) == 2)
                        ((u16*)C)[(size_t)row * N + col] = f2bf(val);
                    else
                        ((float*)C)[(size_t)row * N + col] = val;
                }
        }
    }
}

// O-projection (and any single gemm): 2D grid
template <typename OutT>
__global__ __launch_bounds__(512, 2) void gemm256(const u16* __restrict__ A,
                                                  const u16* __restrict__ Bw,
                                                  const float* __restrict__ bias,
                                                  const float* __restrict__ helix,
                                                  OutT* __restrict__ C,
                                                  int N, int K, int gate) {
    gemm_core<OutT>(A, Bw, bias, helix, C, N, K, blockIdx.y, blockIdx.x, gate, 0);
}

// fused Q+K+V projection: 768 blocks, region = bid>>8 (block-uniform).
__global__ __launch_bounds__(512, 2) void gemm256_qkv(const u16* __restrict__ xbf,
                                                      const u16* __restrict__ Wq,
                                                      const u16* __restrict__ Wk,
                                                      const u16* __restrict__ Wv,
                                                      const float* __restrict__ bq,
                                                      const float* __restrict__ bk,
                                                      const float* __restrict__ bv,
                                                      const float* __restrict__ helix,
                                                      u16* __restrict__ Cq,
                                                      u16* __restrict__ Ck,
                                                      u16* __restrict__ Cv) {
    const int bid = blockIdx.x;
    const int region = bid >> 8;   // 0=Q, 1=K, 2=V
    const int r = bid & 255;
    const u16* A;
    const u16* Bw;
    const float* bias;
    u16* C;
    int tm, tn, gate, vout;
    if (region == 0) {
        A = xbf; Bw = Wq; bias = bq; C = Cq;
        tn = r & 7; tm = r >> 3; gate = 1; vout = 0;
    } else if (region == 1) {
        A = xbf; Bw = Wk; bias = bk; C = Ck;
        tn = r & 7; tm = r >> 3; gate = 2; vout = 0;
    } else {
        A = Wv; Bw = xbf; bias = bv; C = Cv;
        tn = r & 31; tm = r >> 5; gate = 0; vout = 1;
    }
    gemm_core<u16>(A, Bw, bias, helix, C, D_, D_, tm, tn, gate, vout);
}

// ---------------- flash attention: per (b, h, 128-row q tile) ----------------
// V pre-transposed: Vt[b][h][dh][S_]. Unnormalized softmax; l summed from the
// SAME truncated-bf16 P values that feed PV so truncation bias cancels in O/l.
// Round 7: reverted to the round-5 exact kernel (best measured: 212.8us) --
// round 6's 48KB stride-64 variant appears to have regressed (+~?us, untabled).
__global__ __launch_bounds__(256, 2) void helix_attn(const u16* __restrict__ Q,
                                                     const u16* __restrict__ Kq,
                                                     const u16* __restrict__ Vt,
                                                     const float* __restrict__ spiral,
                                                     u16* __restrict__ O) {
    __shared__ __align__(16) u16 Ks[64 * 128];  // [t][d], chunk-XOR swizzled
    __shared__ __align__(16) u16 Vs[128 * 72];  // [d][t], stride 72
    __shared__ __align__(16) u16 Ps[128 * 72];  // [s][t], stride 72, chunk-XOR swz

    const int tid = threadIdx.x;
    const int lane = tid & 63, w = tid >> 6;
    const int lr = lane & 15, quad = lane >> 4;

    const int bx = blockIdx.x;
    const int qt = bx & 15;         // S/128 = 16 q-tiles
    const int h = (bx >> 4) & 15;
    const int b = bx >> 8;

    const size_t headoff = (size_t)b * S_ * D_ + (size_t)h * DH_;
    const u16* qp = Q + headoff;
    const u16* kp = Kq + headoff;
    const u16* vtp = Vt + ((size_t)b * H_ + h) * (size_t)DH_ * S_;

    const float scale2 = spiral[h] * 0.08838834764831845f * 1.4426950408889634f;

    // Q fragments (A-layout), 2 m-blocks per wave, scale2 pre-folded.
    u16x8 qf[2][4];
#pragma unroll
    for (int mb = 0; mb < 2; ++mb)
#pragma unroll
        for (int c = 0; c < 4; ++c) {
            u16x8 raw = *(const u16x8*)(qp + (size_t)(qt * 128 + mb * 64 + w * 16 + lr) * D_ +
                                        c * 32 + quad * 8);
#pragma unroll
            for (int j = 0; j < 8; ++j) {
                float f = __builtin_bit_cast(float, (u32)raw[j] << 16) * scale2;
                qf[mb][c][j] = f2bf(f);
            }
        }

    f32x4 zero = {0.f, 0.f, 0.f, 0.f};
    f32x4 Oacc[2][8];
#pragma unroll
    for (int mb = 0; mb < 2; ++mb)
#pragma unroll
        for (int n = 0; n < 8; ++n) Oacc[mb][n] = zero;
    float rs[2][4] = {{0.f, 0.f, 0.f, 0.f}, {0.f, 0.f, 0.f, 0.f}};

    const int rsw = (lr >> 1) & 7;       // Ps read-side chunk swizzle
    const int wsw = (quad * 2) & 7;      // Ps write-side swizzle base (add r>>1)
    const int ksw = lr & 7;              // Ks read-side chunk swizzle

    for (int tt = 0; tt < 32; ++tt) {
        const int t0 = tt * 64;
        __syncthreads();  // previous iter's K/V reads done
#pragma unroll
        for (int p = 0; p < 4; ++p) {
            int lin = p * 256 + tid;
            int trow = lin >> 4;        // 0..63
            int kch = lin & 15;         // 16B chunks 0..15
            *(u16x8*)&Ks[trow * 128 + ((kch ^ (trow & 7)) * 8)] =
                *(const u16x8*)(kp + (size_t)(t0 + trow) * D_ + kch * 8);
            int drow = lin >> 3;        // 0..127
            int tch = (lin & 7) * 8;    // 0..56
            *(u16x8*)&Vs[drow * 72 + tch] =
                *(const u16x8*)(vtp + (size_t)drow * S_ + t0 + tch);
        }
        __syncthreads();

        // S = Q K^T in log2 units (rows s, cols t = j*16+lr)
        f32x4 Sacc[2][4] = {{zero, zero, zero, zero}, {zero, zero, zero, zero}};
#pragma unroll
        for (int c = 0; c < 4; ++c) {
#pragma unroll
            for (int j = 0; j < 4; ++j) {
                u16x8 kf = *(const u16x8*)&Ks[(j * 16 + lr) * 128 +
                                              (((c * 4 + quad) ^ ksw) * 8)];
                Sacc[0][j] = mfma16(qf[0][c], kf, Sacc[0][j]);
                Sacc[1][j] = mfma16(qf[1][c], kf, Sacc[1][j]);
            }
        }

        // p = 2^s, truncate to bf16; accumulate l from the truncated value.
        // Ps physical col = (chunk ^ ((row>>1)&7))*8 + (col&7)
#pragma unroll
        for (int mb = 0; mb < 2; ++mb)
#pragma unroll
            for (int j = 0; j < 4; ++j)
#pragma unroll
                for (int r = 0; r < 4; ++r) {
                    float p = exp2f(Sacc[mb][j][r]);
                    u32 u = __builtin_bit_cast(u32, p);
                    rs[mb][r] += __builtin_bit_cast(float, u & 0xffff0000u);
                    int prow = mb * 64 + w * 16 + quad * 4 + r;
                    int pchunk = (j * 2 + (lr >> 3)) ^ ((wsw + (r >> 1)) & 7);
                    Ps[prow * 72 + pchunk * 8 + (lr & 7)] = (u16)(u >> 16);
                }

        // O += P V   (Vs is [d][t] = B-fragment layout)
#pragma unroll
        for (int ks = 0; ks < 2; ++ks) {
            int pch = ((ks * 4 + quad) ^ rsw) * 8;
            u16x8 pf0 = *(const u16x8*)&Ps[(w * 16 + lr) * 72 + pch];
            u16x8 pf1 = *(const u16x8*)&Ps[(64 + w * 16 + lr) * 72 + pch];
#pragma unroll
            for (int n = 0; n < 8; ++n) {
                u16x8 vf = *(const u16x8*)&Vs[(n * 16 + lr) * 72 + ks * 32 + quad * 8];
                Oacc[0][n] = mfma16(pf0, vf, Oacc[0][n]);
                Oacc[1][n] = mfma16(pf1, vf, Oacc[1][n]);
            }
        }
    }

    // final: reduce l across the 16 lanes holding each row, normalize, store
#pragma unroll
    for (int mb = 0; mb < 2; ++mb)
#pragma unroll
        for (int r = 0; r < 4; ++r) {
            float s = rs[mb][r];
#pragma unroll
            for (int off = 1; off < 16; off <<= 1) s += __shfl_xor(s, off, 64);
            float inv = 1.0f / s;
            int row = qt * 128 + mb * 64 + w * 16 + quad * 4 + r;
            u16* op = O + headoff + (size_t)row * D_;
#pragma unroll
            for (int n = 0; n < 8; ++n) op[n * 16 + lr] = f2bf(Oacc[mb][n][r] * inv);
        }
}

extern "C" void kernel_launch(void* const* d_in, const int* in_sizes, int n_in,
                              void* d_out, int out_size, void* d_ws, size_t ws_size,
                              hipStream_t stream) {
    const float* x = (const float*)d_in[0];
    const float* Wq = (const float*)d_in[1];
    const float* bq = (const float*)d_in[2];
    const float* Wk = (const float*)d_in[3];
    const float* bk = (const float*)d_in[4];
    const float* Wv = (const float*)d_in[5];
    const float* bv = (const float*)d_in[6];
    const float* Wo = (const float*)d_in[7];
    const float* bo = (const float*)d_in[8];
    const float* spiral = (const float*)d_in[9];
    const float* helix = (const float*)d_in[10];
    float* out = (float*)d_out;

    char* ws = (char*)d_ws;
    // layout (bytes): [x_bf 32M | wq 8M | wk 8M | wv 8M | wo 8M | q 32M | k 32M | vt 32M]
    u16* xbf = (u16*)(ws);
    u16* wqb = (u16*)(ws + 33554432);
    u16* wkb = (u16*)(ws + 33554432 + 8388608);
    u16* wvb = (u16*)(ws + 33554432 + 16777216);
    u16* wob = (u16*)(ws + 33554432 + 25165824);
    u16* qb = (u16*)(ws + 67108864);
    u16* kb = (u16*)(ws + 67108864 + 33554432);
    u16* vtb = (u16*)(ws + 67108864 + 67108864);
    u16* attnb = xbf;

    const int NX = B_ * S_ * D_;  // 16777216

    cvt_f32_bf16<<<NX / 8 / 256, 256, 0, stream>>>(x, xbf, NX / 8);
    // wqb..wob are contiguous: one dispatch for all four weight matrices
    cvt4_f32_bf16<<<4 * 2048, 256, 0, stream>>>(Wq, Wk, Wv, Wo, wqb);

    // fused Q+K+V projection: 768 blocks (3 gemm-equivalents)
    gemm256_qkv<<<768, 512, 0, stream>>>(xbf, wqb, wkb, wvb, bq, bk, bv, helix,
                                         qb, kb, vtb);

    helix_attn<<<B_ * H_ * (S_ / 128), 256, 0, stream>>>(qb, kb, vtb, spiral, attnb);

    dim3 gq(D_ / 256, (B_ * S_) / 256);  // (8, 32)
    gemm256<float><<<gq, 512, 0, stream>>>(attnb, wob, bo, nullptr, out, D_, D_, 0);
}

// Round 8
// 643.329 us; speedup vs baseline: 1.0748x; 1.0748x over previous
//
#include <hip/hip_runtime.h>
#include <math.h>

#define B_ 4
#define S_ 2048
#define D_ 2048
#define H_ 16
#define DH_ 128

typedef unsigned short u16;
typedef unsigned int u32;
typedef u16 u16x8 __attribute__((ext_vector_type(8)));
typedef __bf16 bf16x8 __attribute__((ext_vector_type(8)));
typedef float f32x4 __attribute__((ext_vector_type(4)));

__device__ inline u16 f2bf(float f) {
    // round-to-nearest-even fp32 -> bf16 (inputs are finite)
    unsigned int u = __builtin_bit_cast(unsigned int, f);
    unsigned int lsb = (u >> 16) & 1u;
    u += 0x7fffu + lsb;
    return (u16)(u >> 16);
}

__device__ inline f32x4 mfma16(u16x8 a, u16x8 b, f32x4 c) {
    return __builtin_amdgcn_mfma_f32_16x16x32_bf16(
        __builtin_bit_cast(bf16x8, a), __builtin_bit_cast(bf16x8, b), c, 0, 0, 0);
}

// async global->LDS, 16B per lane; LDS dest = wave-uniform base + lane*16
__device__ inline void gl2lds16(const u16* g, u16* l) {
    __builtin_amdgcn_global_load_lds(
        (const __attribute__((address_space(1))) void*)g,
        (__attribute__((address_space(3))) void*)l, 16, 0, 0);
}

// raw barrier (no vmcnt drain) with compiler memory fences on both sides
__device__ inline void block_barrier() {
    asm volatile("" ::: "memory");
    __builtin_amdgcn_s_barrier();
    asm volatile("" ::: "memory");
}

// ---------------- fp32 -> bf16 conversion (8 elems/thread) ----------------
__global__ __launch_bounds__(256) void cvt_f32_bf16(const float* __restrict__ src,
                                                    u16* __restrict__ dst, int n8) {
    int i = blockIdx.x * 256 + threadIdx.x;
    if (i >= n8) return;
    const float4* s = (const float4*)src + (size_t)i * 2;
    float4 a = s[0], b = s[1];
    u16x8 o;
    o[0] = f2bf(a.x); o[1] = f2bf(a.y); o[2] = f2bf(a.z); o[3] = f2bf(a.w);
    o[4] = f2bf(b.x); o[5] = f2bf(b.y); o[6] = f2bf(b.z); o[7] = f2bf(b.w);
    *((u16x8*)dst + i) = o;
}

// 4 weight matrices (sources separate, dests contiguous) in one dispatch
__global__ __launch_bounds__(256) void cvt4_f32_bf16(const float* __restrict__ s0,
                                                     const float* __restrict__ s1,
                                                     const float* __restrict__ s2,
                                                     const float* __restrict__ s3,
                                                     u16* __restrict__ dst) {
    const int region = blockIdx.x >> 11;         // 2048 blocks per 4M-elem matrix
    const int i = (blockIdx.x & 2047) * 256 + threadIdx.x;  // < 524288 always
    const float* src = region == 0 ? s0 : region == 1 ? s1 : region == 2 ? s2 : s3;
    const float4* s = (const float4*)src + (size_t)i * 2;
    float4 a = s[0], b = s[1];
    u16x8 o;
    o[0] = f2bf(a.x); o[1] = f2bf(a.y); o[2] = f2bf(a.z); o[3] = f2bf(a.w);
    o[4] = f2bf(b.x); o[5] = f2bf(b.y); o[6] = f2bf(b.z); o[7] = f2bf(b.w);
    *((u16x8*)dst + (size_t)region * 524288 + i) = o;
}

// ---------------- C[M,N] = A[M,K] * B[N,K]^T ------------------------------
// 256x256 tile, BK=64, 8 waves (2M x 4N), 4-phase/K-tile, counted vmcnt(6).
// ROUND 8: reverted to the 16x16x32 core (round-6 baseline: 272us qkv, ZERO
// bank conflicts). Round-7's 32x32 A/B: MfmaUtil identical (31.8%) + 1.9e7
// conflicts + slower => MFMA issue rate is NOT the bottleneck; conflict-free
// b128 cycling needs the 16-row fragment pattern. gate/vout runtime, uniform.
template <typename OutT>
__device__ __forceinline__ void gemm_core(const u16* __restrict__ A,
                                          const u16* __restrict__ Bw,
                                          const float* __restrict__ bias,
                                          const float* __restrict__ helix,
                                          OutT* __restrict__ C,
                                          int N, int K,
                                          int tm, int tn, int gate, int vout) {
    __shared__ __align__(16) u16 As[2][256 * 64];
    __shared__ __align__(16) u16 Bs[2][256 * 64];

    const int tid = threadIdx.x;
    const int lane = tid & 63, w = tid >> 6;
    const int lr = lane & 15, quad = lane >> 4;
    const int wm = w & 1, wn = w >> 1;
    const int NT = K >> 6;  // K-tiles of 64

    const u16* Asrc = A + (size_t)(tm * 256) * K;
    const u16* Bsrc = Bw + (size_t)(tn * 256) * K;

    u32 go[4][2];
    u32 lo[4][2];
#pragma unroll
    for (int q = 0; q < 2; ++q) {
        const int seg = w * 2 + q;          // 0..15
        const int i0 = seg * 8 + (lane >> 3);
        const int s0 = seg * 8;
        // U0: A rows {0-63, 128-191} (read in phase 0)
        int row = (i0 & 63) | ((i0 >> 6) << 7);
        int rb = (s0 & 63) | ((s0 >> 6) << 7);
        go[0][q] = (u32)row * K + (((lane & 7) ^ (row & 7)) << 3);
        lo[0][q] = rb << 6;
        // U3: A rows {64-127, 192-255} (read in phases 2-3)
        row += 64; rb += 64;
        go[3][q] = (u32)row * K + (((lane & 7) ^ (row & 7)) << 3);
        lo[3][q] = rb << 6;
        // U1: B rows offset 0-31 (mod 64) (read in phase 0)
        row = (i0 & 31) | ((i0 >> 5) << 6);
        rb = (s0 & 31) | ((s0 >> 5) << 6);
        go[1][q] = (u32)row * K + (((lane & 7) ^ (row & 7)) << 3);
        lo[1][q] = rb << 6;
        // U2: B rows offset 32-63 (read in phase 1)
        row += 32; rb += 32;
        go[2][q] = (u32)row * K + (((lane & 7) ^ (row & 7)) << 3);
        lo[2][q] = rb << 6;
    }

#define STAGE(u, tt)                                                          \
    do {                                                                      \
        const int kt_ = (((tt) < NT) ? (tt) : (NT - 1)) << 6;                 \
        const u16* gb_ = ((u) == 1 || (u) == 2) ? Bsrc : Asrc;                \
        u16* lb_ = ((u) == 1 || (u) == 2) ? Bs[(tt) & 1] : As[(tt) & 1];      \
        gl2lds16(gb_ + go[u][0] + kt_, lb_ + lo[u][0]);                       \
        gl2lds16(gb_ + go[u][1] + kt_, lb_ + lo[u][1]);                       \
    } while (0)

    const int koff0 = (quad * 8) ^ ((lr & 7) * 8);
    const int koff1 = (32 + quad * 8) ^ ((lr & 7) * 8);
    const int rA = wm * 128 + lr;
    const int rB = wn * 64 + lr;

    f32x4 zero = {0.f, 0.f, 0.f, 0.f};
    f32x4 acc[8][4];
#pragma unroll
    for (int im = 0; im < 8; ++im)
#pragma unroll
        for (int jn = 0; jn < 4; ++jn) acc[im][jn] = zero;

    u16x8 af[4][2], bf[4][2];

    STAGE(0, 0); STAGE(1, 0); STAGE(2, 0); STAGE(3, 0);
    STAGE(0, 1); STAGE(1, 1); STAGE(2, 1);
    asm volatile("s_waitcnt vmcnt(6)" ::: "memory");
    block_barrier();

    for (int t = 0; t < NT; ++t) {
        const u16* Ab = As[t & 1];
        const u16* Bb = Bs[t & 1];

        // ---- phase 0: read A m0-3 + B n0-1; stage U3(t+1)
#pragma unroll
        for (int im = 0; im < 4; ++im) {
            af[im][0] = *(const u16x8*)&Ab[(rA + im * 16) * 64 + koff0];
            af[im][1] = *(const u16x8*)&Ab[(rA + im * 16) * 64 + koff1];
        }
#pragma unroll
        for (int jn = 0; jn < 2; ++jn) {
            bf[jn][0] = *(const u16x8*)&Bb[(rB + jn * 16) * 64 + koff0];
            bf[jn][1] = *(const u16x8*)&Bb[(rB + jn * 16) * 64 + koff1];
        }
        STAGE(3, t + 1);
        block_barrier();
        asm volatile("s_waitcnt lgkmcnt(0)" ::: "memory");
        __builtin_amdgcn_s_setprio(1);
#pragma unroll
        for (int s = 0; s < 2; ++s)
#pragma unroll
            for (int im = 0; im < 4; ++im)
#pragma unroll
                for (int jn = 0; jn < 2; ++jn)
                    acc[im][jn] = mfma16(af[im][s], bf[jn][s], acc[im][jn]);
        __builtin_amdgcn_s_setprio(0);
        block_barrier();

        // ---- phase 1: read B n2-3; stage U0(t+2)
#pragma unroll
        for (int jn = 2; jn < 4; ++jn) {
            bf[jn][0] = *(const u16x8*)&Bb[(rB + jn * 16) * 64 + koff0];
            bf[jn][1] = *(const u16x8*)&Bb[(rB + jn * 16) * 64 + koff1];
        }
        STAGE(0, t + 2);
        block_barrier();
        asm volatile("s_waitcnt lgkmcnt(0)" ::: "memory");
        __builtin_amdgcn_s_setprio(1);
#pragma unroll
        for (int s = 0; s < 2; ++s)
#pragma unroll
            for (int im = 0; im < 4; ++im)
#pragma unroll
                for (int jn = 2; jn < 4; ++jn)
                    acc[im][jn] = mfma16(af[im][s], bf[jn][s], acc[im][jn]);
        __builtin_amdgcn_s_setprio(0);
        block_barrier();

        // ---- phase 2: read A m4-7; stage U1(t+2)
#pragma unroll
        for (int im = 0; im < 4; ++im) {
            af[im][0] = *(const u16x8*)&Ab[(rA + 64 + im * 16) * 64 + koff0];
            af[im][1] = *(const u16x8*)&Ab[(rA + 64 + im * 16) * 64 + koff1];
        }
        STAGE(1, t + 2);
        block_barrier();
        asm volatile("s_waitcnt lgkmcnt(0)" ::: "memory");
        __builtin_amdgcn_s_setprio(1);
#pragma unroll
        for (int s = 0; s < 2; ++s)
#pragma unroll
            for (int im = 0; im < 4; ++im)
#pragma unroll
                for (int jn = 0; jn < 2; ++jn)
                    acc[im + 4][jn] = mfma16(af[im][s], bf[jn][s], acc[im + 4][jn]);
        __builtin_amdgcn_s_setprio(0);
        block_barrier();

        // ---- phase 3: stage U2(t+2); counted vmcnt(6) -> tile t+1 confirmed
        STAGE(2, t + 2);
        asm volatile("s_waitcnt vmcnt(6)" ::: "memory");
        block_barrier();
        __builtin_amdgcn_s_setprio(1);
#pragma unroll
        for (int s = 0; s < 2; ++s)
#pragma unroll
            for (int im = 0; im < 4; ++im)
#pragma unroll
                for (int jn = 2; jn < 4; ++jn)
                    acc[im + 4][jn] = mfma16(af[im][s], bf[jn][s], acc[im + 4][jn]);
        __builtin_amdgcn_s_setprio(0);
        block_barrier();
    }
    asm volatile("s_waitcnt vmcnt(0)" ::: "memory");  // drain clamped tail stages
#undef STAGE

    if (vout) {
        // V-mode: row = d in [0,D), col = global t in [0,B*S); bias on row
#pragma unroll
        for (int im = 0; im < 8; ++im)
#pragma unroll
            for (int r = 0; r < 4; ++r) {
                int row = tm * 256 + wm * 128 + im * 16 + quad * 4 + r;
                float bs = bias[row];
#pragma unroll
                for (int jn = 0; jn < 4; ++jn) {
                    int col = tn * 256 + wn * 64 + jn * 16 + lr;
                    float val = acc[im][jn][r] + bs;
                    ((u16*)C)[(size_t)(col >> 11) * ((size_t)D_ * S_) +
                              (size_t)row * S_ + (col & (S_ - 1))] = f2bf(val);
                }
            }
    } else {
#pragma unroll
        for (int jn = 0; jn < 4; ++jn) {
            int col = tn * 256 + wn * 64 + jn * 16 + lr;
            float bs = bias[col];
            float g = 1.0f;
            if (gate == 1) g = cosf(helix[col]);
            if (gate == 2) g = sinf(helix[col]);
#pragma unroll
            for (int im = 0; im < 8; ++im)
#pragma unroll
                for (int r = 0; r < 4; ++r) {
                    int row = tm * 256 + wm * 128 + im * 16 + quad * 4 + r;
                    float val = (acc[im][jn][r] + bs) * g;
                    if constexpr (sizeof(OutT) == 2)
                        ((u16*)C)[(size_t)row * N + col] = f2bf(val);
                    else
                        ((float*)C)[(size_t)row * N + col] = val;
                }
        }
    }
}

// O-projection: 256 blocks, XCD-chunked swizzle (L = xcd*32 + slot): the 8
// tn-blocks of one tm become consecutive-on-one-XCD -> A-panel L2 reuse.
__global__ __launch_bounds__(512, 2) void gemm256_o(const u16* __restrict__ A,
                                                    const u16* __restrict__ Bw,
                                                    const float* __restrict__ bias,
                                                    float* __restrict__ C) {
    const int L = (blockIdx.x & 7) * 32 + (blockIdx.x >> 3);
    gemm_core<float>(A, Bw, bias, nullptr, C, D_, D_, L >> 3, L & 7, 0, 0);
}

// fused Q+K+V projection: 768 blocks. ROUND 8: XCD-chunked swizzle.
// HW dispatches bid round-robin across 8 XCDs (xcd = bid&7, m157 assumption);
// logical L = xcd*96 + (bid>>3) gives each XCD a CONTIGUOUS L-range so blocks
// sharing operand panels are co-resident on one XCD's private L2. Round-6
// counters showed FETCH = 320MB vs ~56MB compulsory (5.7x overfetch) = exactly
// the same-tm-panel-scattered-across-XCDs re-fetch this eliminates.
// V decoded tn-MAJOR (tn = r>>3, tm = r&7): consecutive L share the 1MB xbf
// B-panel (the large reusable operand); Wv (8MB) streams through L2/L3.
__global__ __launch_bounds__(512, 2) void gemm256_qkv(const u16* __restrict__ xbf,
                                                      const u16* __restrict__ Wq,
                                                      const u16* __restrict__ Wk,
                                                      const u16* __restrict__ Wv,
                                                      const float* __restrict__ bq,
                                                      const float* __restrict__ bk,
                                                      const float* __restrict__ bv,
                                                      const float* __restrict__ helix,
                                                      u16* __restrict__ Cq,
                                                      u16* __restrict__ Ck,
                                                      u16* __restrict__ Cv) {
    const int L = (blockIdx.x & 7) * 96 + (blockIdx.x >> 3);
    const int region = L >> 8;   // 0=Q, 1=K, 2=V
    const int r = L & 255;
    const u16* A;
    const u16* Bw;
    const float* bias;
    u16* C;
    int tm, tn, gate, vout;
    if (region == 0) {
        A = xbf; Bw = Wq; bias = bq; C = Cq;
        tn = r & 7; tm = r >> 3; gate = 1; vout = 0;
    } else if (region == 1) {
        A = xbf; Bw = Wk; bias = bk; C = Ck;
        tn = r & 7; tm = r >> 3; gate = 2; vout = 0;
    } else {
        A = Wv; Bw = xbf; bias = bv; C = Cv;
        tn = r >> 3; tm = r & 7; gate = 0; vout = 1;
    }
    gemm_core<u16>(A, Bw, bias, helix, C, D_, D_, tm, tn, gate, vout);
}

// ---------------- flash attention: per (b, h, 128-row q tile) ----------------
// V pre-transposed: Vt[b][h][dh][S_]. Unnormalized softmax; l summed from the
// SAME truncated-bf16 P values that feed PV so truncation bias cancels in O/l.
// (round-5 kernel, best measured 212.8us; untouched this round)
__global__ __launch_bounds__(256, 2) void helix_attn(const u16* __restrict__ Q,
                                                     const u16* __restrict__ Kq,
                                                     const u16* __restrict__ Vt,
                                                     const float* __restrict__ spiral,
                                                     u16* __restrict__ O) {
    __shared__ __align__(16) u16 Ks[64 * 128];  // [t][d], chunk-XOR swizzled
    __shared__ __align__(16) u16 Vs[128 * 72];  // [d][t], stride 72
    __shared__ __align__(16) u16 Ps[128 * 72];  // [s][t], stride 72, chunk-XOR swz

    const int tid = threadIdx.x;
    const int lane = tid & 63, w = tid >> 6;
    const int lr = lane & 15, quad = lane >> 4;

    const int bx = blockIdx.x;
    const int qt = bx & 15;         // S/128 = 16 q-tiles
    const int h = (bx >> 4) & 15;
    const int b = bx >> 8;

    const size_t headoff = (size_t)b * S_ * D_ + (size_t)h * DH_;
    const u16* qp = Q + headoff;
    const u16* kp = Kq + headoff;
    const u16* vtp = Vt + ((size_t)b * H_ + h) * (size_t)DH_ * S_;

    const float scale2 = spiral[h] * 0.08838834764831845f * 1.4426950408889634f;

    // Q fragments (A-layout), 2 m-blocks per wave, scale2 pre-folded.
    u16x8 qf[2][4];
#pragma unroll
    for (int mb = 0; mb < 2; ++mb)
#pragma unroll
        for (int c = 0; c < 4; ++c) {
            u16x8 raw = *(const u16x8*)(qp + (size_t)(qt * 128 + mb * 64 + w * 16 + lr) * D_ +
                                        c * 32 + quad * 8);
#pragma unroll
            for (int j = 0; j < 8; ++j) {
                float f = __builtin_bit_cast(float, (u32)raw[j] << 16) * scale2;
                qf[mb][c][j] = f2bf(f);
            }
        }

    f32x4 zero = {0.f, 0.f, 0.f, 0.f};
    f32x4 Oacc[2][8];
#pragma unroll
    for (int mb = 0; mb < 2; ++mb)
#pragma unroll
        for (int n = 0; n < 8; ++n) Oacc[mb][n] = zero;
    float rs[2][4] = {{0.f, 0.f, 0.f, 0.f}, {0.f, 0.f, 0.f, 0.f}};

    const int rsw = (lr >> 1) & 7;       // Ps read-side chunk swizzle
    const int wsw = (quad * 2) & 7;      // Ps write-side swizzle base (add r>>1)
    const int ksw = lr & 7;              // Ks read-side chunk swizzle

    for (int tt = 0; tt < 32; ++tt) {
        const int t0 = tt * 64;
        __syncthreads();  // previous iter's K/V reads done
#pragma unroll
        for (int p = 0; p < 4; ++p) {
            int lin = p * 256 + tid;
            int trow = lin >> 4;        // 0..63
            int kch = lin & 15;         // 16B chunks 0..15
            *(u16x8*)&Ks[trow * 128 + ((kch ^ (trow & 7)) * 8)] =
                *(const u16x8*)(kp + (size_t)(t0 + trow) * D_ + kch * 8);
            int drow = lin >> 3;        // 0..127
            int tch = (lin & 7) * 8;    // 0..56
            *(u16x8*)&Vs[drow * 72 + tch] =
                *(const u16x8*)(vtp + (size_t)drow * S_ + t0 + tch);
        }
        __syncthreads();

        // S = Q K^T in log2 units (rows s, cols t = j*16+lr)
        f32x4 Sacc[2][4] = {{zero, zero, zero, zero}, {zero, zero, zero, zero}};
#pragma unroll
        for (int c = 0; c < 4; ++c) {
#pragma unroll
            for (int j = 0; j < 4; ++j) {
                u16x8 kf = *(const u16x8*)&Ks[(j * 16 + lr) * 128 +
                                              (((c * 4 + quad) ^ ksw) * 8)];
                Sacc[0][j] = mfma16(qf[0][c], kf, Sacc[0][j]);
                Sacc[1][j] = mfma16(qf[1][c], kf, Sacc[1][j]);
            }
        }

        // p = 2^s, truncate to bf16; accumulate l from the truncated value.
        // Ps physical col = (chunk ^ ((row>>1)&7))*8 + (col&7)
#pragma unroll
        for (int mb = 0; mb < 2; ++mb)
#pragma unroll
            for (int j = 0; j < 4; ++j)
#pragma unroll
                for (int r = 0; r < 4; ++r) {
                    float p = exp2f(Sacc[mb][j][r]);
                    u32 u = __builtin_bit_cast(u32, p);
                    rs[mb][r] += __builtin_bit_cast(float, u & 0xffff0000u);
                    int prow = mb * 64 + w * 16 + quad * 4 + r;
                    int pchunk = (j * 2 + (lr >> 3)) ^ ((wsw + (r >> 1)) & 7);
                    Ps[prow * 72 + pchunk * 8 + (lr & 7)] = (u16)(u >> 16);
                }

        // O += P V   (Vs is [d][t] = B-fragment layout)
#pragma unroll
        for (int ks = 0; ks < 2; ++ks) {
            int pch = ((ks * 4 + quad) ^ rsw) * 8;
            u16x8 pf0 = *(const u16x8*)&Ps[(w * 16 + lr) * 72 + pch];
            u16x8 pf1 = *(const u16x8*)&Ps[(64 + w * 16 + lr) * 72 + pch];
#pragma unroll
            for (int n = 0; n < 8; ++n) {
                u16x8 vf = *(const u16x8*)&Vs[(n * 16 + lr) * 72 + ks * 32 + quad * 8];
                Oacc[0][n] = mfma16(pf0, vf, Oacc[0][n]);
                Oacc[1][n] = mfma16(pf1, vf, Oacc[1][n]);
            }
        }
    }

    // final: reduce l across the 16 lanes holding each row, normalize, store
#pragma unroll
    for (int mb = 0; mb < 2; ++mb)
#pragma unroll
        for (int r = 0; r < 4; ++r) {
            float s = rs[mb][r];
#pragma unroll
            for (int off = 1; off < 16; off <<= 1) s += __shfl_xor(s, off, 64);
            float inv = 1.0f / s;
            int row = qt * 128 + mb * 64 + w * 16 + quad * 4 + r;
            u16* op = O + headoff + (size_t)row * D_;
#pragma unroll
            for (int n = 0; n < 8; ++n) op[n * 16 + lr] = f2bf(Oacc[mb][n][r] * inv);
        }
}

extern "C" void kernel_launch(void* const* d_in, const int* in_sizes, int n_in,
                              void* d_out, int out_size, void* d_ws, size_t ws_size,
                              hipStream_t stream) {
    const float* x = (const float*)d_in[0];
    const float* Wq = (const float*)d_in[1];
    const float* bq = (const float*)d_in[2];
    const float* Wk = (const float*)d_in[3];
    const float* bk = (const float*)d_in[4];
    const float* Wv = (const float*)d_in[5];
    const float* bv = (const float*)d_in[6];
    const float* Wo = (const float*)d_in[7];
    const float* bo = (const float*)d_in[8];
    const float* spiral = (const float*)d_in[9];
    const float* helix = (const float*)d_in[10];
    float* out = (float*)d_out;

    char* ws = (char*)d_ws;
    // layout (bytes): [x_bf 32M | wq 8M | wk 8M | wv 8M | wo 8M | q 32M | k 32M | vt 32M]
    u16* xbf = (u16*)(ws);
    u16* wqb = (u16*)(ws + 33554432);
    u16* wkb = (u16*)(ws + 33554432 + 8388608);
    u16* wvb = (u16*)(ws + 33554432 + 16777216);
    u16* wob = (u16*)(ws + 33554432 + 25165824);
    u16* qb = (u16*)(ws + 67108864);
    u16* kb = (u16*)(ws + 67108864 + 33554432);
    u16* vtb = (u16*)(ws + 67108864 + 67108864);
    u16* attnb = xbf;

    const int NX = B_ * S_ * D_;  // 16777216

    cvt_f32_bf16<<<NX / 8 / 256, 256, 0, stream>>>(x, xbf, NX / 8);
    // wqb..wob are contiguous: one dispatch for all four weight matrices
    cvt4_f32_bf16<<<4 * 2048, 256, 0, stream>>>(Wq, Wk, Wv, Wo, wqb);

    // fused Q+K+V projection: 768 blocks (3 gemm-equivalents), XCD-swizzled
    gemm256_qkv<<<768, 512, 0, stream>>>(xbf, wqb, wkb, wvb, bq, bk, bv, helix,
                                         qb, kb, vtb);

    helix_attn<<<B_ * H_ * (S_ / 128), 256, 0, stream>>>(qb, kb, vtb, spiral, attnb);

    gemm256_o<<<256, 512, 0, stream>>>(attnb, wob, bo, out);
}